// Round 6
// baseline (548.781 us; speedup 1.0000x reference)
//
#include <hip/hip_runtime.h>

// ---------------------------------------------------------------------------
// AttentionLayer (weight-norm in/out proj + softmax cross-attention)
// N=16, TQ=TS=C=E=1024, fp32 in/out.
// Split-fp32 GEMMs on bf16 MFMA. Score path (GEMM1/2) = 3-pass split;
// GEMM3 = bf16; GEMM4 = 2-pass.
//
// R4: source-swizzled LDS (bank conflicts 8.4M -> 0, neutral -> not the path).
// R5: T3-minimum 2-phase pipeline: double-buffered LDS, prefetch next K-tile
//     BEFORE computing current, raw s_barrier + manual vmcnt(0) (one barrier
//     per K-step instead of two; load latency hidden under MFMA+ds_read).
//
// Memory plan (ws 72MB):
//   ws:   [0,2)Wi_h [2,4)Wi_l [4,6)Wo_h [6,8)Wo_l
//         [8,40)KT_h -> attn_hi     [40,72)KT_l -> ctx_hi          (MB)
//   d_out.out  [0,64MB):  x-split -> scores f32 -> VT_h bf16 -> out
//   d_out.attn [64,128MB): h-split -> attn f32 (final output)
// ---------------------------------------------------------------------------

typedef __bf16 bf16_t;
typedef bf16_t bf16x8 __attribute__((ext_vector_type(8)));
typedef bf16_t bf16x4 __attribute__((ext_vector_type(4)));
typedef float f32x4 __attribute__((ext_vector_type(4)));

constexpr int BM = 128, BN = 128, BK = 32;
#define SQRT_HALF 0.7071067811865476f

__device__ __forceinline__ void stage16(const bf16_t* g, void* lds) {
  __builtin_amdgcn_global_load_lds(
      (const __attribute__((address_space(1))) unsigned int*)g,
      (__attribute__((address_space(3))) unsigned int*)lds, 16, 0, 0);
}

__device__ __forceinline__ void split_store(bf16_t* ph, bf16_t* pl, float v) {
  bf16_t h = (bf16_t)v;
  *ph = h;
  *pl = (bf16_t)(v - (float)h);
}

// --------------------------- weight norm (dim=0) ---------------------------
__global__ __launch_bounds__(256) void wnorm_split_kernel(
    const float* __restrict__ v, const float* __restrict__ g,
    bf16_t* __restrict__ oh, bf16_t* __restrict__ ol, int C)
{
  int row = blockIdx.x;
  const float* vr = v + (long)row * C;
  float ss = 0.f;
  for (int c = threadIdx.x; c < C; c += 256) { float x = vr[c]; ss += x * x; }
#pragma unroll
  for (int m = 1; m < 64; m <<= 1) ss += __shfl_xor(ss, m, 64);
  __shared__ float red[4];
  if ((threadIdx.x & 63) == 0) red[threadIdx.x >> 6] = ss;
  __syncthreads();
  float tot = red[0] + red[1] + red[2] + red[3];
  float scale = g[row] / sqrtf(tot);
  for (int c = threadIdx.x; c < C; c += 256) {
    float w = vr[c] * scale;
    split_store(&oh[(long)row * C + c], &ol[(long)row * C + c], w);
  }
}

// ------------------------- f32 -> bf16 hi/lo split -------------------------
__global__ __launch_bounds__(256) void split_f32_kernel(
    const float* __restrict__ x, bf16_t* __restrict__ oh,
    bf16_t* __restrict__ ol, long n4)
{
  long i = (long)blockIdx.x * 256 + threadIdx.x;
  long stride = (long)gridDim.x * 256;
  for (; i < n4; i += stride) {
    float4 v = reinterpret_cast<const float4*>(x)[i];
    bf16x4 hv, lv;
    hv[0] = (bf16_t)v.x; lv[0] = (bf16_t)(v.x - (float)hv[0]);
    hv[1] = (bf16_t)v.y; lv[1] = (bf16_t)(v.y - (float)hv[1]);
    hv[2] = (bf16_t)v.z; lv[2] = (bf16_t)(v.z - (float)hv[2]);
    hv[3] = (bf16_t)v.w; lv[3] = (bf16_t)(v.w - (float)hv[3]);
    *reinterpret_cast<bf16x4*>(&oh[i * 4]) = hv;
    *reinterpret_cast<bf16x4*>(&ol[i * 4]) = lv;
  }
}

// -------------------- transpose + split: [z][R][C] -> [z][C][R] ------------
__global__ __launch_bounds__(256) void transpose_split_kernel(
    const float* __restrict__ in, bf16_t* __restrict__ oh,
    bf16_t* __restrict__ ol, int R, int C)
{
  __shared__ float t[32][33];
  long zb = (long)blockIdx.z * R * C;
  int r0 = blockIdx.y * 32, c0 = blockIdx.x * 32;
  int tx = threadIdx.x & 31, ty = threadIdx.x >> 5;
#pragma unroll
  for (int i = 0; i < 4; ++i)
    t[ty + i * 8][tx] = in[zb + (long)(r0 + ty + i * 8) * C + c0 + tx];
  __syncthreads();
#pragma unroll
  for (int i = 0; i < 4; ++i) {
    int oc = ty + i * 8;
    float v = t[tx][oc];
    long oi = zb + (long)(c0 + oc) * R + r0 + tx;
    bf16_t h = (bf16_t)v;
    oh[oi] = h;
    if (ol) ol[oi] = (bf16_t)(v - (float)h);
  }
}

// ------------------------------- GEMM --------------------------------------
// C[M][Nn] = A[M][K] * Bt[Nn][K]^T, NPASS: 1 = Ah*Bh, 2 = +Ah*Bl, 3 = +Al*Bh
// 2-phase pipeline: prefetch K-tile t+1 into buf[cur^1] before computing
// buf[cur]; one vmcnt(0)+s_barrier per K-step.
// LDS source-swizzle: slot (row,s) holds chunk (row, s^((row>>1)&3)).
template <int EPI, int NPASS>
__global__ __launch_bounds__(256, 2) void gemm_kernel(
    const bf16_t* __restrict__ Ah, const bf16_t* __restrict__ Al,
    const bf16_t* __restrict__ Bh, const bf16_t* __restrict__ Bl,
    int K, long sAb, long sBb,
    const float* __restrict__ bias, const float* __restrict__ addt,
    float scale, float* __restrict__ outF,
    bf16_t* __restrict__ outH, bf16_t* __restrict__ outL,
    long sOb, int Nn)
{
  const int n = blockIdx.z;
  Ah += (long)n * sAb; Bh += (long)n * sBb;
  if constexpr (NPASS >= 3) Al += (long)n * sAb;
  if constexpr (NPASS >= 2) Bl += (long)n * sBb;
  const long ob = (long)n * sOb;

  const int row0 = blockIdx.x * BM, col0 = blockIdx.y * BN;
  const int tid = threadIdx.x;
  const int l = tid & 63;
  const int wr = (tid >> 6) >> 1, wc = (tid >> 6) & 1;   // 2x2 wave grid
  const int lr = l & 15, lq = l >> 4;

  // double-buffered tiles, 8KB each
  __shared__ __align__(16) bf16_t Ash[2 * BM * BK];
  __shared__ __align__(16) bf16_t Bsh[2 * BN * BK];
  __shared__ __align__(16) bf16_t Asl[NPASS >= 3 ? 2 * BM * BK : 8];
  __shared__ __align__(16) bf16_t Bsl[NPASS >= 2 ? 2 * BN * BK : 8];

  // staging: LDS dest linear, global source column pre-swizzled
  const int r1 = tid >> 2;                             // rows 0..63
  const int r2 = r1 + 64;                              // rows 64..127 (same key)
  const int c1 = (((tid & 3) ^ ((r1 >> 1) & 3))) * 8;  // swizzled source col
  const int wb = (tid * 16) & ~1023;                   // wave-uniform LDS base

  const long aoff1 = (long)(row0 + r1) * K + c1;
  const long aoff2 = (long)(row0 + r2) * K + c1;
  const long boff1 = (long)(col0 + r1) * K + c1;
  const long boff2 = (long)(col0 + r2) * K + c1;

  // fragment-read swizzle key
  const int fkey = (lr >> 1) & 3;
  const int fcol = (lq ^ fkey) * 8;

  f32x4 acc[4][4] = {};

  auto STAGE = [&](int half, int k0) {
    const int hb = half * 8192;  // bytes
    stage16(Ah + aoff1 + k0, (char*)Ash + hb + wb);
    stage16(Ah + aoff2 + k0, (char*)Ash + hb + 4096 + wb);
    stage16(Bh + boff1 + k0, (char*)Bsh + hb + wb);
    stage16(Bh + boff2 + k0, (char*)Bsh + hb + 4096 + wb);
    if constexpr (NPASS >= 3) {
      stage16(Al + aoff1 + k0, (char*)Asl + hb + wb);
      stage16(Al + aoff2 + k0, (char*)Asl + hb + 4096 + wb);
    }
    if constexpr (NPASS >= 2) {
      stage16(Bl + boff1 + k0, (char*)Bsl + hb + wb);
      stage16(Bl + boff2 + k0, (char*)Bsl + hb + 4096 + wb);
    }
  };

  auto COMPUTE = [&](int half) {
    const int he = half * BM * BK;  // elements
    bf16x8 afh[4], afl[4], bfh[4], bfl[4];
#pragma unroll
    for (int mf = 0; mf < 4; ++mf) {
      int ar = wr * 64 + mf * 16 + lr;
      afh[mf] = *reinterpret_cast<const bf16x8*>(&Ash[he + ar * BK + fcol]);
      if constexpr (NPASS >= 3)
        afl[mf] = *reinterpret_cast<const bf16x8*>(&Asl[he + ar * BK + fcol]);
    }
#pragma unroll
    for (int nf = 0; nf < 4; ++nf) {
      int br = wc * 64 + nf * 16 + lr;
      bfh[nf] = *reinterpret_cast<const bf16x8*>(&Bsh[he + br * BK + fcol]);
      if constexpr (NPASS >= 2)
        bfl[nf] = *reinterpret_cast<const bf16x8*>(&Bsl[he + br * BK + fcol]);
    }
#pragma unroll
    for (int mf = 0; mf < 4; ++mf)
#pragma unroll
      for (int nf = 0; nf < 4; ++nf) {
        acc[mf][nf] = __builtin_amdgcn_mfma_f32_16x16x32_bf16(afh[mf], bfh[nf], acc[mf][nf], 0, 0, 0);
        if constexpr (NPASS >= 2)
          acc[mf][nf] = __builtin_amdgcn_mfma_f32_16x16x32_bf16(afh[mf], bfl[nf], acc[mf][nf], 0, 0, 0);
        if constexpr (NPASS >= 3)
          acc[mf][nf] = __builtin_amdgcn_mfma_f32_16x16x32_bf16(afl[mf], bfh[nf], acc[mf][nf], 0, 0, 0);
      }
  };

  // prologue: stage tile 0, drain, barrier
  STAGE(0, 0);
  asm volatile("s_waitcnt vmcnt(0)" ::: "memory");
  __builtin_amdgcn_s_barrier();
  asm volatile("" ::: "memory");

  int cur = 0;
  for (int k0 = BK; k0 < K; k0 += BK) {
    STAGE(cur ^ 1, k0);      // issue next-tile loads (latency hides under compute)
    COMPUTE(cur);
    asm volatile("s_waitcnt vmcnt(0)" ::: "memory");
    __builtin_amdgcn_s_barrier();
    asm volatile("" ::: "memory");
    cur ^= 1;
  }
  COMPUTE(cur);              // epilogue tile (no prefetch)

#pragma unroll
  for (int mf = 0; mf < 4; ++mf)
#pragma unroll
    for (int nf = 0; nf < 4; ++nf)
#pragma unroll
      for (int r = 0; r < 4; ++r) {
        int row = row0 + wr * 64 + mf * 16 + lq * 4 + r;  // C/D: row=(l>>4)*4+r
        int col = col0 + wc * 64 + nf * 16 + lr;          //      col=l&15
        long gi = (long)row * Nn + col;
        float v = acc[mf][nf][r];
        if constexpr (EPI == 0) {
          float h = (v + bias[col] + addt[gi]) * scale;
          split_store(&outH[gi], &outL[gi], h);
        } else if constexpr (EPI == 1) {
          outF[ob + gi] = v;
        } else if constexpr (EPI == 2) {
          outH[ob + gi] = (bf16_t)(v * scale);
        } else {
          outF[gi] = (v + bias[col] + addt[gi]) * scale;
        }
      }
}

// ---------------- softmax (rows of 1024): src -> dstF + hi bf16 ------------
__global__ __launch_bounds__(256) void softmax_kernel(
    const float* __restrict__ src, float* __restrict__ dstF,
    bf16_t* __restrict__ ah)
{
  long row = blockIdx.x;
  const float* p = src + row * 1024;
  int t = threadIdx.x;
  float4 v = reinterpret_cast<const float4*>(p)[t];
  float m = fmaxf(fmaxf(v.x, v.y), fmaxf(v.z, v.w));
#pragma unroll
  for (int mask = 1; mask < 64; mask <<= 1) m = fmaxf(m, __shfl_xor(m, mask, 64));
  __shared__ float red[4], red2[4];
  if ((t & 63) == 0) red[t >> 6] = m;
  __syncthreads();
  m = fmaxf(fmaxf(red[0], red[1]), fmaxf(red[2], red[3]));
  float e0 = expf(v.x - m), e1 = expf(v.y - m);
  float e2 = expf(v.z - m), e3 = expf(v.w - m);
  float s = e0 + e1 + e2 + e3;
#pragma unroll
  for (int mask = 1; mask < 64; mask <<= 1) s += __shfl_xor(s, mask, 64);
  if ((t & 63) == 0) red2[t >> 6] = s;
  __syncthreads();
  s = red2[0] + red2[1] + red2[2] + red2[3];
  float inv = 1.f / s;
  float a0 = e0 * inv, a1 = e1 * inv, a2 = e2 * inv, a3 = e3 * inv;
  reinterpret_cast<float4*>(dstF + row * 1024)[t] = make_float4(a0, a1, a2, a3);
  bf16x4 hv;
  hv[0] = (bf16_t)a0; hv[1] = (bf16_t)a1; hv[2] = (bf16_t)a2; hv[3] = (bf16_t)a3;
  *reinterpret_cast<bf16x4*>(&ah[row * 1024 + (long)t * 4]) = hv;
}

// ---------------------------------------------------------------------------
extern "C" void kernel_launch(void* const* d_in, const int* in_sizes, int n_in,
                              void* d_out, int out_size, void* d_ws, size_t ws_size,
                              hipStream_t stream)
{
  (void)in_sizes; (void)n_in; (void)out_size; (void)ws_size;
  const float* x   = (const float*)d_in[0];
  const float* te  = (const float*)d_in[1];
  const float* ek  = (const float*)d_in[2];
  const float* ev  = (const float*)d_in[3];
  const float* ipv = (const float*)d_in[4];
  const float* ipg = (const float*)d_in[5];
  const float* ipb = (const float*)d_in[6];
  const float* opv = (const float*)d_in[7];
  const float* opg = (const float*)d_in[8];
  const float* opb = (const float*)d_in[9];

  const long M1 = 1024L * 1024L;
  float* out   = (float*)d_out;                       // [16,1024,1024]
  float* attnF = out + 16 * M1;                       // [16,1024,1024]

  // ws (72MB total)
  char* ws = (char*)d_ws;
  bf16_t* Wi_h = (bf16_t*)(ws);
  bf16_t* Wi_l = (bf16_t*)(ws + (2L << 20));
  bf16_t* Wo_h = (bf16_t*)(ws + (4L << 20));
  bf16_t* Wo_l = (bf16_t*)(ws + (6L << 20));
  bf16_t* KT_h = (bf16_t*)(ws + (8L << 20));
  bf16_t* KT_l = (bf16_t*)(ws + (40L << 20));
  bf16_t* at_h = KT_h;                 // attn_hi reuses KT_h (dead after GEMM2)
  bf16_t* cx_h = KT_l;                 // ctx_hi  reuses KT_l (dead after GEMM2)

  // d_out scratch regions
  bf16_t* x_h = (bf16_t*)d_out;                       // [0,32MB)
  bf16_t* x_l = x_h + 16 * M1;                        // [32,64MB)
  float* scores = out;                                // [0,64MB) after x dead
  bf16_t* VT_h = (bf16_t*)d_out;                      // [0,32MB) after scores dead
  bf16_t* h_h = (bf16_t*)attnF;                       // [64,96MB)
  bf16_t* h_l = h_h + 16 * M1;                        // [96,128MB)

  // 1-2. weight norm -> split
  wnorm_split_kernel<<<dim3(1024), dim3(256), 0, stream>>>(ipv, ipg, Wi_h, Wi_l, 1024);
  wnorm_split_kernel<<<dim3(1024), dim3(256), 0, stream>>>(opv, opg, Wo_h, Wo_l, 1024);
  // 3. split x -> d_out.out
  split_f32_kernel<<<dim3(2048), dim3(256), 0, stream>>>(x, x_h, x_l, 16 * M1 / 4);
  // 4. KT[n][s][e] = ek[n][e][s] (split, ws)
  transpose_split_kernel<<<dim3(32, 32, 16), dim3(256), 0, stream>>>(ek, KT_h, KT_l, 1024, 1024);
  // 5. GEMM1: h = (x @ Wi^T + b + te) * sqrt(.5) -> split into d_out.attn
  gemm_kernel<0, 3><<<dim3(128, 8, 1), dim3(256), 0, stream>>>(
      x_h, x_l, Wi_h, Wi_l, 1024, 0L, 0L, ipb, te, SQRT_HALF,
      nullptr, h_h, h_l, 0L, 1024);
  // 6. GEMM2: scores = h @ K -> f32 d_out.out (x-split dead)
  gemm_kernel<1, 3><<<dim3(8, 8, 16), dim3(256), 0, stream>>>(
      h_h, h_l, KT_h, KT_l, 1024, M1, M1, nullptr, nullptr, 1.0f,
      scores, nullptr, nullptr, M1, 1024);
  // 7. softmax: scores -> attn f32 (d_out.attn, h dead) + attn_hi (ws KT_h slot)
  softmax_kernel<<<dim3(16384), dim3(256), 0, stream>>>(scores, attnF, at_h);
  // 8. VT[n][e][s] = ev[n][s][e] (hi only) -> d_out[0,32MB) (scores dead)
  transpose_split_kernel<<<dim3(32, 32, 16), dim3(256), 0, stream>>>(ev, VT_h, nullptr, 1024, 1024);
  // 9. GEMM3: ctx = (attn @ V) * 32 -> bf16 ctx_hi (ws KT_l slot)
  gemm_kernel<2, 1><<<dim3(8, 8, 16), dim3(256), 0, stream>>>(
      at_h, nullptr, VT_h, nullptr, 1024, M1, M1, nullptr, nullptr, 32.0f,
      nullptr, cx_h, nullptr, M1, 1024);
  // 10. GEMM4: out = (ctx @ Wo^T + b + x) * sqrt(.5) -> f32 d_out.out
  gemm_kernel<3, 2><<<dim3(128, 8, 1), dim3(256), 0, stream>>>(
      cx_h, nullptr, Wo_h, Wo_l, 1024, 0L, 0L, opb, x, SQRT_HALF,
      out, nullptr, nullptr, 0L, 1024);
}

// Round 7
// 406.331 us; speedup vs baseline: 1.3506x; 1.3506x over previous
//
#include <hip/hip_runtime.h>

// ---------------------------------------------------------------------------
// AttentionLayer (weight-norm in/out proj + softmax cross-attention)
// N=16, TQ=TS=C=E=1024, fp32 in/out.
//
// R7: all four GEMMs in ONE fp16 MFMA pass (error model: softmax Jacobian
// <= 0.25 caps attn err at 0.25*logit_err ~= 0.008; out absmax ~0.3 << 2.8).
// GEMM1/GEMM3 reg-stage their f32 A operand (x / attn) with in-flight f32->f16
// conversion into swizzled LDS; B operands staged via global_load_lds with
// source-swizzle (R4, conflicts = 0). Single-buffer 2-barrier loop (R4 won
// over R6's explicit dbuf).
//
// Memory plan (ws 68MB < 72 proven):
//   ws:  [0,2) Wi16  [2,4) Wo16  [4,36) VT16  [36,68) KT16 -> ctx16
//   d_out.out  [0,64MB):  scores f32 (GEMM2) -> out f32 (GEMM4)
//   d_out.attn [64,128MB): h16 (GEMM1, first 32MB) -> attn f32 (softmax, final)
// Inputs never written; every d_out byte rewritten each call.
// ---------------------------------------------------------------------------

typedef _Float16 f16_t;
typedef f16_t f16x8 __attribute__((ext_vector_type(8)));
typedef float f32x4 __attribute__((ext_vector_type(4)));

constexpr int BM = 128, BN = 128, BK = 32;
#define SQRT_HALF 0.7071067811865476f

__device__ __forceinline__ void stage16(const f16_t* g, void* lds) {
  __builtin_amdgcn_global_load_lds(
      (const __attribute__((address_space(1))) unsigned int*)g,
      (__attribute__((address_space(3))) unsigned int*)lds, 16, 0, 0);
}

// --------------------------- weight norm (dim=0) ---------------------------
__global__ __launch_bounds__(256) void wnorm_f16_kernel(
    const float* __restrict__ v, const float* __restrict__ g,
    f16_t* __restrict__ o, int C)
{
  int row = blockIdx.x;
  const float* vr = v + (long)row * C;
  float ss = 0.f;
  for (int c = threadIdx.x; c < C; c += 256) { float x = vr[c]; ss += x * x; }
#pragma unroll
  for (int m = 1; m < 64; m <<= 1) ss += __shfl_xor(ss, m, 64);
  __shared__ float red[4];
  if ((threadIdx.x & 63) == 0) red[threadIdx.x >> 6] = ss;
  __syncthreads();
  float tot = red[0] + red[1] + red[2] + red[3];
  float scale = g[row] / sqrtf(tot);
  for (int c = threadIdx.x; c < C; c += 256)
    o[(long)row * C + c] = (f16_t)(vr[c] * scale);
}

// ------------------ transpose f32 -> f16: [z][R][C] -> [z][C][R] -----------
__global__ __launch_bounds__(256) void transpose_f16_kernel(
    const float* __restrict__ in, f16_t* __restrict__ o, int R, int C)
{
  __shared__ float t[32][33];
  long zb = (long)blockIdx.z * R * C;
  int r0 = blockIdx.y * 32, c0 = blockIdx.x * 32;
  int tx = threadIdx.x & 31, ty = threadIdx.x >> 5;
#pragma unroll
  for (int i = 0; i < 4; ++i)
    t[ty + i * 8][tx] = in[zb + (long)(r0 + ty + i * 8) * C + c0 + tx];
  __syncthreads();
#pragma unroll
  for (int i = 0; i < 4; ++i) {
    int oc = ty + i * 8;
    o[zb + (long)(c0 + oc) * R + r0 + tx] = (f16_t)t[tx][oc];
  }
}

// ------------------------------- GEMM (fp16) -------------------------------
// C[M][Nn] = A[M][K] * Bt[Nn][K]^T.
// AF32: A is f32 in global; reg-staged (load float4 x4, cvt, ds_write_b128 x2)
//       into the same swizzled LDS layout. Else: f16 A via global_load_lds
//       with source-swizzle. LDS slot (row,s) holds chunk (row, s^((row>>1)&3)).
// EPI 0: h   = (acc + bias[col] + addt[gi]) * scale -> f16 outH
// EPI 1: scores = acc                               -> f32 outF (batched)
// EPI 2: ctx = acc * scale                          -> f16 outH (batched)
// EPI 3: out = (acc + bias[col] + addt[gi]) * scale -> f32 outF
template <int EPI, bool AF32>
__global__ __launch_bounds__(256) void gemm_f16_kernel(
    const void* __restrict__ Ap, const f16_t* __restrict__ B,
    int K, long sAb, long sBb,
    const float* __restrict__ bias, const float* __restrict__ addt,
    float scale, float* __restrict__ outF, f16_t* __restrict__ outH,
    long sOb, int Nn)
{
  const int n = blockIdx.z;
  B += (long)n * sBb;
  const long ob = (long)n * sOb;

  const int row0 = blockIdx.x * BM, col0 = blockIdx.y * BN;
  const int tid = threadIdx.x;
  const int l = tid & 63;
  const int wr = (tid >> 6) >> 1, wc = (tid >> 6) & 1;   // 2x2 wave grid
  const int lr = l & 15, lq = l >> 4;

  __shared__ __align__(16) f16_t Ash[BM * BK];
  __shared__ __align__(16) f16_t Bsh[BN * BK];

  // gload_lds staging geometry (B always; A when !AF32)
  const int r1 = tid >> 2;                               // rows 0..63
  const int r2 = r1 + 64;                                // rows 64..127
  const int c1e = (((tid & 3) ^ ((r1 >> 1) & 3))) * 8;   // swizzled source col
  const int wb = (tid * 16) & ~1023;                     // wave-uniform base
  const long boff1 = (long)(col0 + r1) * K + c1e;
  const long boff2 = (long)(col0 + r2) * K + c1e;

  // AF32 reg-staging geometry: thread -> (row, 16-col half)
  const float* Af = nullptr;
  const f16_t* Ah = nullptr;
  long abase = 0, aoff1 = 0, aoff2 = 0;
  char *awp0 = nullptr, *awp1 = nullptr;
  if constexpr (AF32) {
    Af = (const float*)Ap + (long)n * sAb;
    const int ar_ = tid >> 1, hh = tid & 1;
    abase = (long)(row0 + ar_) * K + hh * 16;
    const int s0 = (2 * hh) ^ ((ar_ >> 1) & 3);
    awp0 = (char*)Ash + ar_ * 64 + s0 * 16;
    awp1 = (char*)Ash + ar_ * 64 + (s0 ^ 1) * 16;
  } else {
    Ah = (const f16_t*)Ap + (long)n * sAb;
    aoff1 = (long)(row0 + r1) * K + c1e;
    aoff2 = (long)(row0 + r2) * K + c1e;
  }

  // fragment-read swizzle
  const int fcol = (lq ^ ((lr >> 1) & 3)) * 8;

  f32x4 acc[4][4] = {};

  for (int k0 = 0; k0 < K; k0 += BK) {
    __syncthreads();
    if constexpr (AF32) {
      const float4* p = (const float4*)(Af + abase + k0);
      float4 v0 = p[0], v1 = p[1], v2 = p[2], v3 = p[3];
      f16x8 c0, c1;
      c0[0] = (f16_t)v0.x; c0[1] = (f16_t)v0.y; c0[2] = (f16_t)v0.z; c0[3] = (f16_t)v0.w;
      c0[4] = (f16_t)v1.x; c0[5] = (f16_t)v1.y; c0[6] = (f16_t)v1.z; c0[7] = (f16_t)v1.w;
      c1[0] = (f16_t)v2.x; c1[1] = (f16_t)v2.y; c1[2] = (f16_t)v2.z; c1[3] = (f16_t)v2.w;
      c1[4] = (f16_t)v3.x; c1[5] = (f16_t)v3.y; c1[6] = (f16_t)v3.z; c1[7] = (f16_t)v3.w;
      *reinterpret_cast<f16x8*>(awp0) = c0;
      *reinterpret_cast<f16x8*>(awp1) = c1;
    } else {
      stage16(Ah + aoff1 + k0, (char*)Ash + wb);
      stage16(Ah + aoff2 + k0, (char*)Ash + 4096 + wb);
    }
    stage16(B + boff1 + k0, (char*)Bsh + wb);
    stage16(B + boff2 + k0, (char*)Bsh + 4096 + wb);
    __syncthreads();

    f16x8 af[4], bf[4];
#pragma unroll
    for (int mf = 0; mf < 4; ++mf)
      af[mf] = *reinterpret_cast<const f16x8*>(&Ash[(wr * 64 + mf * 16 + lr) * BK + fcol]);
#pragma unroll
    for (int nf = 0; nf < 4; ++nf)
      bf[nf] = *reinterpret_cast<const f16x8*>(&Bsh[(wc * 64 + nf * 16 + lr) * BK + fcol]);
#pragma unroll
    for (int mf = 0; mf < 4; ++mf)
#pragma unroll
      for (int nf = 0; nf < 4; ++nf)
        acc[mf][nf] = __builtin_amdgcn_mfma_f32_16x16x32_f16(af[mf], bf[nf], acc[mf][nf], 0, 0, 0);
  }

#pragma unroll
  for (int mf = 0; mf < 4; ++mf)
#pragma unroll
    for (int nf = 0; nf < 4; ++nf)
#pragma unroll
      for (int r = 0; r < 4; ++r) {
        int row = row0 + wr * 64 + mf * 16 + lq * 4 + r;  // C/D: row=(l>>4)*4+r
        int col = col0 + wc * 64 + nf * 16 + lr;          //      col=l&15
        long gi = (long)row * Nn + col;
        float v = acc[mf][nf][r];
        if constexpr (EPI == 0) {
          outH[gi] = (f16_t)((v + bias[col] + addt[gi]) * scale);
        } else if constexpr (EPI == 1) {
          outF[ob + gi] = v;
        } else if constexpr (EPI == 2) {
          outH[ob + gi] = (f16_t)(v * scale);
        } else {
          outF[gi] = (v + bias[col] + addt[gi]) * scale;
        }
      }
}

// ---------------- softmax (rows of 1024): f32 -> f32 -----------------------
__global__ __launch_bounds__(256) void softmax_kernel(
    const float* __restrict__ src, float* __restrict__ dstF)
{
  long row = blockIdx.x;
  const float* p = src + row * 1024;
  int t = threadIdx.x;
  float4 v = reinterpret_cast<const float4*>(p)[t];
  float m = fmaxf(fmaxf(v.x, v.y), fmaxf(v.z, v.w));
#pragma unroll
  for (int mask = 1; mask < 64; mask <<= 1) m = fmaxf(m, __shfl_xor(m, mask, 64));
  __shared__ float red[4], red2[4];
  if ((t & 63) == 0) red[t >> 6] = m;
  __syncthreads();
  m = fmaxf(fmaxf(red[0], red[1]), fmaxf(red[2], red[3]));
  float e0 = expf(v.x - m), e1 = expf(v.y - m);
  float e2 = expf(v.z - m), e3 = expf(v.w - m);
  float s = e0 + e1 + e2 + e3;
#pragma unroll
  for (int mask = 1; mask < 64; mask <<= 1) s += __shfl_xor(s, mask, 64);
  if ((t & 63) == 0) red2[t >> 6] = s;
  __syncthreads();
  s = red2[0] + red2[1] + red2[2] + red2[3];
  float inv = 1.f / s;
  reinterpret_cast<float4*>(dstF + row * 1024)[t] =
      make_float4(e0 * inv, e1 * inv, e2 * inv, e3 * inv);
}

// ---------------------------------------------------------------------------
extern "C" void kernel_launch(void* const* d_in, const int* in_sizes, int n_in,
                              void* d_out, int out_size, void* d_ws, size_t ws_size,
                              hipStream_t stream)
{
  (void)in_sizes; (void)n_in; (void)out_size; (void)ws_size;
  const float* x   = (const float*)d_in[0];
  const float* te  = (const float*)d_in[1];
  const float* ek  = (const float*)d_in[2];
  const float* ev  = (const float*)d_in[3];
  const float* ipv = (const float*)d_in[4];
  const float* ipg = (const float*)d_in[5];
  const float* ipb = (const float*)d_in[6];
  const float* opv = (const float*)d_in[7];
  const float* opg = (const float*)d_in[8];
  const float* opb = (const float*)d_in[9];

  const long M1 = 1024L * 1024L;
  float* out   = (float*)d_out;                       // [16,1024,1024]
  float* attnF = out + 16 * M1;                       // [16,1024,1024]

  // ws (68MB total)
  char* ws = (char*)d_ws;
  f16_t* Wi16  = (f16_t*)(ws);                        // [0,2)
  f16_t* Wo16  = (f16_t*)(ws + (2L << 20));           // [2,4)
  f16_t* VT16  = (f16_t*)(ws + (4L << 20));           // [4,36)
  f16_t* KT16  = (f16_t*)(ws + (36L << 20));          // [36,68)
  f16_t* ctx16 = KT16;                                // reuse (KT dead after GEMM2)

  // d_out scratch
  float* scores = out;                                // [0,64MB), dead after softmax
  f16_t* h16 = (f16_t*)attnF;                         // [64,96MB), dead after GEMM2

  // 1. weight norm -> f16
  wnorm_f16_kernel<<<dim3(1024), dim3(256), 0, stream>>>(ipv, ipg, Wi16, 1024);
  wnorm_f16_kernel<<<dim3(1024), dim3(256), 0, stream>>>(opv, opg, Wo16, 1024);
  // 2. transposes: KT[n][s][e] = ek[n][e][s]; VT[n][e][s] = ev[n][s][e]
  transpose_f16_kernel<<<dim3(32, 32, 16), dim3(256), 0, stream>>>(ek, KT16, 1024, 1024);
  transpose_f16_kernel<<<dim3(32, 32, 16), dim3(256), 0, stream>>>(ev, VT16, 1024, 1024);
  // 3. GEMM1: h = (x @ Wi^T + b + te) * sqrt(.5) -> f16 (A = x f32, reg-staged)
  gemm_f16_kernel<0, true><<<dim3(128, 8, 1), dim3(256), 0, stream>>>(
      x, Wi16, 1024, 0L, 0L, ipb, te, SQRT_HALF, nullptr, h16, 0L, 1024);
  // 4. GEMM2: scores = h @ K -> f32 d_out.out (batched)
  gemm_f16_kernel<1, false><<<dim3(8, 8, 16), dim3(256), 0, stream>>>(
      h16, KT16, 1024, M1, M1, nullptr, nullptr, 1.0f, scores, nullptr, M1, 1024);
  // 5. softmax: scores -> attn f32 (d_out.attn; h16 dead)
  softmax_kernel<<<dim3(16384), dim3(256), 0, stream>>>(scores, attnF);
  // 6. GEMM3: ctx = (attn @ V) * 32 -> f16 ws (A = attnF f32, reg-staged)
  gemm_f16_kernel<2, true><<<dim3(8, 8, 16), dim3(256), 0, stream>>>(
      attnF, VT16, 1024, M1, M1, nullptr, nullptr, 32.0f, nullptr, ctx16, M1, 1024);
  // 7. GEMM4: out = (ctx @ Wo^T + b + x) * sqrt(.5) -> f32 d_out.out
  gemm_f16_kernel<3, false><<<dim3(128, 8, 1), dim3(256), 0, stream>>>(
      ctx16, Wo16, 1024, 0L, 0L, opb, x, SQRT_HALF, out, nullptr, 0L, 1024);
}